// Round 14
// baseline (79.715 us; speedup 1.0000x reference)
//
#include <hip/hip_runtime.h>

#define HH 136
#define WW 240
#define HW (HH * WW)
#define DS 8
#define OW (DS * WW)   // 1920
#define OH (DS * HH)   // 1088
#define NCH 9          // chunk = one k (8 j-rows x 2 h)
#define NBUF 2         // lookahead 1 (R11-proven)

typedef float vf4 __attribute__((ext_vector_type(4)));

// H-PAIR blocks: R8-R13 showed schedule structure is invariant (~75 us);
// the shared element is the access pattern (72 x 960 B scattered segments
// per block; chip-wide ~random 1KB-granule reads over 300 MB). mask rows
// h, h+1 of a channel are CONTIGUOUS, so a block owning an h-pair stages
// 1920 B contiguous per (k,j): 2x DRAM burst, half the concurrent streams.
// (R12 corroborates: shrinking to 240 B requests regressed.)
//  - 512 threads = 8 waves; wave w stages channel j=w: two back-to-back
//    960 B gload_lds (rows h0, h0+1 -> adjacent addresses).
//  - R11 pipeline: NBUF=2, issue c+1, counted vmcnt(2), 2 raw barriers.
//  - LDS [2][8][2][240] = 30.7 KB -> 4 blocks/CU x 8 waves = 32 waves/CU.
//  - compute: thread (ph=tid/240, px=tid%240) handles output row
//    (h0+ph)*8+i; LDS reads stride-1 (2 lanes/bank, free).
//  - no-max softmax (verified R6-R13); R4 store shape (thread owns
//    32 B/channel, block writes dense 1920-float rows).
__device__ __forceinline__ void gload_lds16(const float* g, float* l) {
  __builtin_amdgcn_global_load_lds(
      (const __attribute__((address_space(1))) void*)g,
      (__attribute__((address_space(3))) void*)l, 16, 0, 0);
}

__global__ __launch_bounds__(512, 4) void upflow_kernel(
    const float* __restrict__ flow,
    const float* __restrict__ mask,
    float* __restrict__ out) {
  __shared__ float lm[NBUF][8][2][WW];  // 30720 B

  int h0 = blockIdx.x * 2;  // h-pair base, 0..134
  int ni = blockIdx.y;      // n*8 + i
  int i = ni & 7;
  int n = ni >> 3;
  int tid = threadIdx.x;
  int w = tid >> 6, lane = tid & 63;
  int ph = tid / 240;        // 0 or 1 (2 => inactive)
  int px = tid - ph * 240;   // column 0..239
  bool act = tid < 480;
  int h = h0 + ph;

  // mask base for (n, i, h0); wave w's chunk-k segment is
  // (k*64 + w)*HW + {0, WW}: two adjacent 960 B rows = 1920 B contiguous.
  const float* mrow = mask + ((size_t)n * 576 + i * 8) * HW + (size_t)h0 * WW;

  // Prologue: stage chunk 0 into buf 0 (issued before flow loads would
  // matter; flow is tiny and L2/L3-resident).
  if (lane < 60) {
    const float* b = mrow + (size_t)w * HW;
    gload_lds16(b + lane * 4, &lm[0][w][0][0]);
    gload_lds16(b + WW + lane * 4, &lm[0][w][1][0]);
  }

  // 3x3 flow neighborhood for row h, both channels, pre-scaled, padded.
  float f0[9], f1[9];
  if (act) {
    const float* fb0 = flow + (size_t)(n * 2 + 0) * HW;
    const float* fb1 = flow + (size_t)(n * 2 + 1) * HW;
#pragma unroll
    for (int dy = 0; dy < 3; ++dy) {
      int hh = h + dy - 1;
      bool rok = (hh >= 0) && (hh < HH);
#pragma unroll
      for (int dx = 0; dx < 3; ++dx) {
        int k = dy * 3 + dx;
        int cc = px + dx - 1;
        bool ok = rok && (cc >= 0) && (cc < WW);
        int idx = hh * WW + cc;
        f0[k] = ok ? 8.0f * fb0[idx] : 0.0f;
        f1[k] = ok ? 8.0f * fb1[idx] : 0.0f;
      }
    }
  }

  const float L2E = 1.4426950408889634f;
  float sj[8], d0j[8], d1j[8];
#pragma unroll
  for (int j = 0; j < 8; ++j) { sj[j] = 0.f; d0j[j] = 0.f; d1j[j] = 0.f; }

#pragma unroll
  for (int c = 0; c < NCH; ++c) {
    if (c + 1 < NCH) {
      // Issue chunk c+1 into buf (c+1)&1 (its readers finished at the
      // barrier closing chunk c-1 — R11-proven).
      if (lane < 60) {
        const float* b = mrow + (size_t)((c + 1) * 64 + w) * HW;
        gload_lds16(b + lane * 4, &lm[(c + 1) & 1][w][0][0]);
        gload_lds16(b + WW + lane * 4, &lm[(c + 1) & 1][w][1][0]);
      }
      // Batch c landed; batch c+1 (2 loads) stays in flight.
      asm volatile("s_waitcnt vmcnt(2)" ::: "memory");
    } else {
      asm volatile("s_waitcnt vmcnt(0)" ::: "memory");
    }
    __builtin_amdgcn_s_barrier();   // batch c visible to all waves
    asm volatile("" ::: "memory");  // ds_reads may not hoist above

    if (act) {
      const float fc0 = f0[c], fc1 = f1[c];  // chunk == k
#pragma unroll
      for (int j = 0; j < 8; ++j) {
        float e = exp2f(lm[c & 1][j][ph][px] * L2E);  // no max-subtraction
        sj[j] += e;
        d0j[j] += e * fc0;
        d1j[j] += e * fc1;
      }
    }

    if (c + 1 < NCH) {
      asm volatile("" ::: "memory");  // ds_reads may not sink below
      __builtin_amdgcn_s_barrier();   // chunk-c reads done; refill legal
      asm volatile("" ::: "memory");
    }
  }

  if (act) {
    // out[n][c][h*8+i][px*8+j]: 32 B contiguous per lane per channel; block
    // writes two fully dense 1920-float rows per channel (R4 shape).
    size_t ob0 =
        ((size_t)(n * 2 + 0) * OH + (size_t)(h * 8 + i)) * (size_t)OW + px * 8;
    size_t ob1 = ob0 + (size_t)OH * OW;
    float r0 = 1.0f / sj[0], r1 = 1.0f / sj[1], r2 = 1.0f / sj[2],
          r3 = 1.0f / sj[3], r4 = 1.0f / sj[4], r5 = 1.0f / sj[5],
          r6 = 1.0f / sj[6], r7 = 1.0f / sj[7];
    vf4 a = {d0j[0] * r0, d0j[1] * r1, d0j[2] * r2, d0j[3] * r3};
    vf4 b = {d0j[4] * r4, d0j[5] * r5, d0j[6] * r6, d0j[7] * r7};
    vf4 c = {d1j[0] * r0, d1j[1] * r1, d1j[2] * r2, d1j[3] * r3};
    vf4 d = {d1j[4] * r4, d1j[5] * r5, d1j[6] * r6, d1j[7] * r7};
    *(vf4*)(out + ob0) = a;
    *(vf4*)(out + ob0 + 4) = b;
    *(vf4*)(out + ob1) = c;
    *(vf4*)(out + ob1 + 4) = d;
  }
}

extern "C" void kernel_launch(void* const* d_in, const int* in_sizes, int n_in,
                              void* d_out, int out_size, void* d_ws, size_t ws_size,
                              hipStream_t stream) {
  const float* flow = (const float*)d_in[0];
  const float* mask = (const float*)d_in[1];
  float* out = (float*)d_out;
  dim3 grid(HH / 2, 32);  // x = h-pair, y = n*8 + i
  upflow_kernel<<<grid, 512, 0, stream>>>(flow, mask, out);
}